// Round 1
// baseline (569.067 us; speedup 1.0000x reference)
//
#include <hip/hip_runtime.h>
#include <hip/hip_bf16.h>

typedef unsigned short u16;
typedef u16 u16x4 __attribute__((ext_vector_type(4)));
typedef __bf16 bf16x8 __attribute__((ext_vector_type(8)));
typedef float f32x4 __attribute__((ext_vector_type(4)));

#define IN_DIM 4096
#define OUT_DIM 4096
#define M_TOT 8192   // 4 * 2048

__device__ __constant__ float NF4_LUT[16] = {
    -1.0f, -0.6961928009986877f, -0.5250730514526367f, -0.39491748809814453f,
    -0.28444138169288635f, -0.18477343022823334f, -0.09105003625154495f, 0.0f,
    0.07958029955625534f, 0.16093020141124725f, 0.24611230194568634f,
    0.33791524171829224f, 0.44070982933044434f, 0.5626170039176941f,
    0.7229568362236023f, 1.0f};

__device__ __forceinline__ u16 f2bf(float f) {  // round-to-nearest-even
  unsigned i = __float_as_uint(f);
  i += 0x7fffu + ((i >> 16) & 1u);
  return (u16)(i >> 16);
}

// ---------------------------------------------------------------------------
// Kernel 0: cast x fp32 -> bf16 into workspace.
// ---------------------------------------------------------------------------
__global__ __launch_bounds__(256) void convert_x(
    const float4* __restrict__ xin, u16x4* __restrict__ xout, int n4)
{
  int i = blockIdx.x * 256 + threadIdx.x;
  const int stride = gridDim.x * 256;
  for (; i < n4; i += stride) {
    const float4 v = xin[i];
    u16x4 o;
    o.x = f2bf(v.x); o.y = f2bf(v.y); o.z = f2bf(v.z); o.w = f2bf(v.w);
    xout[i] = o;
  }
}

// ---------------------------------------------------------------------------
// Kernel 1: dequantize NF4 -> fp32, fold LoRA (W_eff = W + 2*B*A), store bf16.
// ---------------------------------------------------------------------------
__global__ __launch_bounds__(256) void dequant_fold(
    const int* __restrict__ nf4_idx, const int* __restrict__ q_scalers,
    const float* __restrict__ q_factor, const float* __restrict__ scaler_mean,
    const float* __restrict__ lora_a, const float* __restrict__ lora_b,
    u16* __restrict__ w_eff)
{
  __shared__ float s_lut[16];
  __shared__ float s_b[16];
  __shared__ float s_scl[64];
  const int t = threadIdx.x;
  const int o = blockIdx.x;
  if (t < 16) {
    s_lut[t] = NF4_LUT[t];
    s_b[t] = 2.0f * lora_b[o * 16 + t];   // ALPHA/RANK = 2 folded here
  }
  if (t < 64) {
    const int b = o * 64 + t;             // nf4-block index within this row
    s_scl[t] = (float)q_scalers[b] / q_factor[b >> 8] + scaler_mean[0];
  }
  __syncthreads();

  float Bf[16];
#pragma unroll
  for (int r = 0; r < 16; ++r) Bf[r] = s_b[r];

#pragma unroll
  for (int it = 0; it < 4; ++it) {
    const int d0 = it * 1024 + t * 4;
    const int4 iv = *(const int4*)(nf4_idx + (size_t)o * IN_DIM + d0);
    const float sc = s_scl[d0 >> 6];
    float l0 = 0.f, l1 = 0.f, l2 = 0.f, l3 = 0.f;
#pragma unroll
    for (int r = 0; r < 16; ++r) {
      const float4 av = *(const float4*)(lora_a + (size_t)r * IN_DIM + d0);
      const float br = Bf[r];
      l0 += br * av.x;
      l1 += br * av.y;
      l2 += br * av.z;
      l3 += br * av.w;
    }
    u16x4 ov;
    ov.x = f2bf(s_lut[iv.x] * sc + l0);
    ov.y = f2bf(s_lut[iv.y] * sc + l1);
    ov.z = f2bf(s_lut[iv.z] * sc + l2);
    ov.w = f2bf(s_lut[iv.w] * sc + l3);
    *(u16x4*)(w_eff + (size_t)o * IN_DIM + d0) = ov;
  }
}

// ---------------------------------------------------------------------------
// Kernel 2: bf16 GEMM, 256x256 8-phase structure (m201 template, plain HIP).
// C[M,N] = X[M,K] * W[N,K]^T.  BM=BN=256, BK=64, 512 threads = 8 waves (2Mx4N),
// per-wave 128x64 output = 8x4 reps of mfma_f32_16x16x32_bf16.
// LDS: 128 KiB, double-buffered A/B K-tiles, chunk-XOR swizzle (chunk ^= row&7)
// realized as linear global_load_lds dest + inverse-swizzled global source +
// swizzled ds_read (rule #21).  Counted vmcnt(8) at K-tile end (T4), setprio
// around MFMA clusters (T5), 4 phases x 16 MFMA per K-tile (T3).
// ---------------------------------------------------------------------------
#define BM 256
#define BN 256
#define BK 64
#define NT (IN_DIM / BK)   // 64 K-tiles

__device__ __forceinline__ void async16(const u16* g, const u16* l) {
  __builtin_amdgcn_global_load_lds(
      (const __attribute__((address_space(1))) void*)g,
      (__attribute__((address_space(3))) void*)l,
      16, 0, 0);
}

// Stage one 64-row group (j) of A and B for buffer c at k-offset kt.
// Wave-uniform LDS base (chunk j*512 + wid*64); HW adds lane*16B.
// Global source row = base + j*64 + (tid>>3), chunk = (tid&7) ^ ((tid>>3)&7)
// -- the inverse swizzle, so that swizzled ds_read below sees logical data.
#define STG(c, kt, j) do {                                                     \
    async16(gA + (size_t)(j) * 64 * IN_DIM + (kt),                             \
            &sA[(c) * BM * BK + ((j) * 512 + wid * 64) * 8]);                  \
    async16(gB + (size_t)(j) * 64 * IN_DIM + (kt),                             \
            &sB[(c) * BN * BK + ((j) * 512 + wid * 64) * 8]);                  \
  } while (0)

#define MFMA_Q(AF, BF, MI0) do {                                               \
    _Pragma("unroll") for (int mi = (MI0); mi < (MI0) + 4; ++mi)               \
    _Pragma("unroll") for (int ni = 0; ni < 4; ++ni)                           \
      acc[mi][ni] = __builtin_amdgcn_mfma_f32_16x16x32_bf16(                   \
          AF[mi], BF[ni], acc[mi][ni], 0, 0, 0);                               \
  } while (0)

// One K-tile = 4 phases.  Phases 1-2: all 24 ds_reads of buf c (+32 MFMA);
// phases 3-4: stage next-next K-tile into buf c (+32 MFMA).  WAR-safe: all
// reads of buf c complete (lgkmcnt(0)) before the phase-2 end barrier, and
// staging is issued only after that barrier.
#define KTILE(c, ktn, DOSTAGE, ENDVM_STR, DOENDBAR) do {                       \
  /* phase 1: read A k0 (8), B k0 (4); MFMA k0 x mi0-3 */                      \
  _Pragma("unroll") for (int mi = 0; mi < 8; ++mi)                             \
    a0[mi] = *(const bf16x8*)&sA[(c) * BM * BK + aBase + mi * 1024 + e0];      \
  _Pragma("unroll") for (int ni = 0; ni < 4; ++ni)                             \
    b0[ni] = *(const bf16x8*)&sB[(c) * BN * BK + bBase + ni * 1024 + e0];      \
  __builtin_amdgcn_s_barrier();                                                \
  asm volatile("s_waitcnt lgkmcnt(0)" ::: "memory");                           \
  __builtin_amdgcn_s_setprio(1);                                               \
  MFMA_Q(a0, b0, 0);                                                           \
  __builtin_amdgcn_s_setprio(0);                                               \
  __builtin_amdgcn_s_barrier();                                                \
  /* phase 2: read A k1 (8), B k1 (4); MFMA k0 x mi4-7 */                      \
  _Pragma("unroll") for (int mi = 0; mi < 8; ++mi)                             \
    a1[mi] = *(const bf16x8*)&sA[(c) * BM * BK + aBase + mi * 1024 + e1];      \
  _Pragma("unroll") for (int ni = 0; ni < 4; ++ni)                             \
    b1[ni] = *(const bf16x8*)&sB[(c) * BN * BK + bBase + ni * 1024 + e1];      \
  __builtin_amdgcn_s_barrier();                                                \
  asm volatile("s_waitcnt lgkmcnt(0)" ::: "memory");                           \
  __builtin_amdgcn_s_setprio(1);                                               \
  MFMA_Q(a0, b0, 4);                                                           \
  __builtin_amdgcn_s_setprio(0);                                               \
  __builtin_amdgcn_s_barrier();                                                \
  /* phase 3: stage half of next-next tile; MFMA k1 x mi0-3 */                 \
  if (DOSTAGE) { STG(c, ktn, 0); STG(c, ktn, 1); }                             \
  __builtin_amdgcn_s_barrier();                                                \
  __builtin_amdgcn_s_setprio(1);                                               \
  MFMA_Q(a1, b1, 0);                                                           \
  __builtin_amdgcn_s_setprio(0);                                               \
  __builtin_amdgcn_s_barrier();                                                \
  /* phase 4: stage other half; MFMA k1 x mi4-7; counted vmcnt */              \
  if (DOSTAGE) { STG(c, ktn, 2); STG(c, ktn, 3); }                             \
  __builtin_amdgcn_s_barrier();                                                \
  __builtin_amdgcn_s_setprio(1);                                               \
  MFMA_Q(a1, b1, 4);                                                           \
  __builtin_amdgcn_s_setprio(0);                                               \
  asm volatile("s_waitcnt " ENDVM_STR ::: "memory");                           \
  if (DOENDBAR) __builtin_amdgcn_s_barrier();                                  \
} while (0)

__global__ __launch_bounds__(512, 2) void gemm256(
    const u16* __restrict__ X, const u16* __restrict__ W,
    float* __restrict__ Out)
{
  __shared__ __align__(16) u16 sA[2 * BM * BK];   // 64 KiB
  __shared__ __align__(16) u16 sB[2 * BN * BK];   // 64 KiB

  const int tid = threadIdx.x;
  const int lane = tid & 63;
  const int wid = tid >> 6;          // 0..7
  const int wm = wid >> 2;           // 0..1  (M half)
  const int wn = wid & 3;            // 0..3  (N quarter)

  // XCD-bijective block swizzle: 512 wgs, 512 % 8 == 0 -> simple form valid.
  const int bid = blockIdx.x;
  const int swzb = (bid & 7) * 64 + (bid >> 3);
  const int tileM = swzb >> 4;       // 0..31
  const int tileN = swzb & 15;       // 0..15
  const int rowBase = tileM * BM;
  const int colBase = tileN * BN;

  // Staging source: row-group row (tid>>3), inverse-swizzled chunk.
  const int cr = tid >> 3;           // 0..63
  const int cq = tid & 7;            // 0..7
  const int qsw = cq ^ (cr & 7);
  const u16* gA = X + (size_t)(rowBase + cr) * IN_DIM + qsw * 8;
  const u16* gB = W + (size_t)(colBase + cr) * IN_DIM + qsw * 8;

  // ds_read fragment addressing (swizzled): row r = base + l15 (+mi*16),
  // chunk q = krep*4 + (lane>>4), physical chunk = q ^ (r&7) = q ^ (lane&7).
  const int l15 = lane & 15;
  const int qhi = lane >> 4;         // 0..3
  const int l7 = lane & 7;
  const int e0 = (qhi ^ l7) * 8;           // krep 0 chunk offset (elems)
  const int e1 = ((4 + qhi) ^ l7) * 8;     // krep 1
  const int aBase = (wm * 128 + l15) * 64;
  const int bBase = (wn * 64 + l15) * 64;

  f32x4 acc[8][4] = {};
  bf16x8 a0[8], a1[8], b0[4], b1[4];

  // Prologue: stage K-tiles 0 (buf0) and 1 (buf1); wait tile 0 only.
  STG(0, 0, 0); STG(0, 0, 1); STG(0, 0, 2); STG(0, 0, 3);
  STG(1, BK, 0); STG(1, BK, 1); STG(1, BK, 2); STG(1, BK, 3);
  asm volatile("s_waitcnt vmcnt(8)" ::: "memory");
  __builtin_amdgcn_s_barrier();

  // Main loop: 62 K-tiles, each staging K-tile t+2 and ending vmcnt(8).
  int kt2 = 2 * BK;
  for (int t = 0; t < NT - 2; t += 2) {
    KTILE(0, kt2, true, "vmcnt(8)", true);
    KTILE(1, kt2 + BK, true, "vmcnt(8)", true);
    kt2 += 2 * BK;
  }
  // Epilogue: last two K-tiles, no staging; drain before the final tile.
  KTILE(0, 0, false, "vmcnt(0)", true);
  KTILE(1, 0, false, "vmcnt(0)", false);

  // C/D layout: col = lane&15 (+ni*16), row = (lane>>4)*4 + i.  fp32 stores.
  const int or4 = qhi * 4;
#pragma unroll
  for (int mi = 0; mi < 8; ++mi) {
#pragma unroll
    for (int i = 0; i < 4; ++i) {
      const size_t r = (size_t)(rowBase + wm * 128 + mi * 16 + or4 + i);
      float* po = Out + r * OUT_DIM + colBase + wn * 64 + l15;
#pragma unroll
      for (int ni = 0; ni < 4; ++ni)
        po[ni * 16] = acc[mi][ni][i];
    }
  }
}

extern "C" void kernel_launch(void* const* d_in, const int* in_sizes, int n_in,
                              void* d_out, int out_size, void* d_ws, size_t ws_size,
                              hipStream_t stream) {
  const float* x         = (const float*)d_in[0];
  const int* nf4_idx     = (const int*)d_in[1];
  const int* q_scalers   = (const int*)d_in[2];
  const float* q_factor  = (const float*)d_in[3];
  const float* scaler_mean = (const float*)d_in[4];
  const float* lora_a    = (const float*)d_in[5];
  const float* lora_b    = (const float*)d_in[6];
  float* out = (float*)d_out;

  // ws layout: [0, 64MB) x as bf16; [64MB, 96MB) W_eff as bf16.
  const size_t xbf_bytes = (size_t)M_TOT * IN_DIM * sizeof(u16);
  const size_t wef_bytes = (size_t)OUT_DIM * IN_DIM * sizeof(u16);
  if (ws_size < xbf_bytes + wef_bytes) return;  // need 96 MB
  u16* xbf   = (u16*)d_ws;
  u16* w_eff = (u16*)((char*)d_ws + xbf_bytes);

  hipLaunchKernelGGL(convert_x, dim3(8192), dim3(256), 0, stream,
                     (const float4*)x, (u16x4*)xbf, M_TOT * IN_DIM / 4);
  hipLaunchKernelGGL(dequant_fold, dim3(OUT_DIM), dim3(256), 0, stream,
                     nf4_idx, q_scalers, q_factor, scaler_mean, lora_a, lora_b,
                     w_eff);
  hipLaunchKernelGGL(gemm256, dim3((M_TOT / BM) * (OUT_DIM / BN)), dim3(512),
                     0, stream, xbf, w_eff, out);
}